// Round 1
// baseline (70.494 us; speedup 1.0000x reference)
//
#include <hip/hip_runtime.h>
#include <math.h>

// densemap = sum_k c_k * log2(relu(k^2 * conv_k(x)) + 1)
// conv_k = separable Gaussian (sigma = k/2), TF-SAME padding: pad_lo = (k-1)/2.
// Column/row window offsets union: -2..+3 (6 wide).

struct Weights {
    float wh[6][6]; // horizontal 1D gaussian weights, prescaled by k^2
    float wv[6][6]; // vertical 1D gaussian weights
    float c[6];     // regression slope coefficients
};

#define TILE 32
#define LDSW 37   // TILE + 5 halo (offsets -2..+3)

__global__ __launch_bounds__(256) void ldeb_kernel(const float* __restrict__ x,
                                                   float* __restrict__ out,
                                                   Weights W) {
    __shared__ float xs[LDSW * LDSW];
    const int img = blockIdx.z;
    const int x0 = blockIdx.x * TILE - 2;
    const int y0 = blockIdx.y * TILE - 2;
    const float* xb = x + (size_t)img * 512 * 512;
    const int tid = threadIdx.y * 32 + threadIdx.x;

    // stage 37x37 halo tile (zero-fill outside image)
    for (int i = tid; i < LDSW * LDSW; i += 256) {
        int r = i / LDSW;
        int c = i - r * LDSW;
        int gy = y0 + r;
        int gx = x0 + c;
        float v = 0.0f;
        if ((unsigned)gy < 512u && (unsigned)gx < 512u)
            v = xb[gy * 512 + gx];
        xs[i] = v;
    }
    __syncthreads();

    const int lc = threadIdx.x;           // local col 0..31
    const int R0 = threadIdx.y * 4;       // local row base (4 rows/thread)

    // horizontal passes: 9 rows needed for 4 outputs (window rows R-2..R+3)
    float H[9][6];
#pragma unroll
    for (int rr = 0; rr < 9; ++rr) {
        const float* row = &xs[(R0 + rr) * LDSW + lc];
        float v0 = row[0], v1 = row[1], v2 = row[2],
              v3 = row[3], v4 = row[4], v5 = row[5];
        H[rr][0] = v2 * W.wh[0][0];
        H[rr][1] = v2 * W.wh[1][0] + v3 * W.wh[1][1];
        H[rr][2] = v1 * W.wh[2][0] + v2 * W.wh[2][1] + v3 * W.wh[2][2];
        H[rr][3] = v1 * W.wh[3][0] + v2 * W.wh[3][1] + v3 * W.wh[3][2]
                 + v4 * W.wh[3][3];
        H[rr][4] = v0 * W.wh[4][0] + v1 * W.wh[4][1] + v2 * W.wh[4][2]
                 + v3 * W.wh[4][3] + v4 * W.wh[4][4];
        H[rr][5] = v0 * W.wh[5][0] + v1 * W.wh[5][1] + v2 * W.wh[5][2]
                 + v3 * W.wh[5][3] + v4 * W.wh[5][4] + v5 * W.wh[5][5];
    }

    const int gx_out = blockIdx.x * TILE + lc;
    float* ob = out + (size_t)img * 512 * 512;

#pragma unroll
    for (int r = 0; r < 4; ++r) {
        // vertical passes (pad_lo per k: 0,0,1,1,2,2)
        float s1 = H[r + 2][0] * W.wv[0][0];
        float s2 = H[r + 2][1] * W.wv[1][0] + H[r + 3][1] * W.wv[1][1];
        float s3 = H[r + 1][2] * W.wv[2][0] + H[r + 2][2] * W.wv[2][1]
                 + H[r + 3][2] * W.wv[2][2];
        float s4 = H[r + 1][3] * W.wv[3][0] + H[r + 2][3] * W.wv[3][1]
                 + H[r + 3][3] * W.wv[3][2] + H[r + 4][3] * W.wv[3][3];
        float s5 = H[r + 0][4] * W.wv[4][0] + H[r + 1][4] * W.wv[4][1]
                 + H[r + 2][4] * W.wv[4][2] + H[r + 3][4] * W.wv[4][3]
                 + H[r + 4][4] * W.wv[4][4];
        float s6 = H[r + 0][5] * W.wv[5][0] + H[r + 1][5] * W.wv[5][1]
                 + H[r + 2][5] * W.wv[5][2] + H[r + 3][5] * W.wv[5][3]
                 + H[r + 4][5] * W.wv[5][4] + H[r + 5][5] * W.wv[5][5];

        float y1 = log2f(fmaxf(s1, 0.0f) + 1.0f);
        float y2 = log2f(fmaxf(s2, 0.0f) + 1.0f);
        float y3 = log2f(fmaxf(s3, 0.0f) + 1.0f);
        float y4 = log2f(fmaxf(s4, 0.0f) + 1.0f);
        float y5 = log2f(fmaxf(s5, 0.0f) + 1.0f);
        float y6 = log2f(fmaxf(s6, 0.0f) + 1.0f);

        float acc = W.c[0] * y1 + W.c[1] * y2 + W.c[2] * y3
                  + W.c[3] * y4 + W.c[4] * y5 + W.c[5] * y6;

        int gy = blockIdx.y * TILE + R0 + r;
        ob[gy * 512 + gx_out] = acc;
    }
}

extern "C" void kernel_launch(void* const* d_in, const int* in_sizes, int n_in,
                              void* d_out, int out_size, void* d_ws, size_t ws_size,
                              hipStream_t stream) {
    const float* x = (const float*)d_in[0];
    float* out = (float*)d_out;

    Weights W;
    // regression coefficients: c_k = (X_k - mean(X)) / sum((X - mean)^2), X_k = log2(k)
    double X[6], mean = 0.0;
    for (int k = 1; k <= 6; ++k) { X[k - 1] = log2((double)k); mean += X[k - 1]; }
    mean /= 6.0;
    double denom = 0.0;
    for (int i = 0; i < 6; ++i) { double xc = X[i] - mean; denom += xc * xc; }
    for (int i = 0; i < 6; ++i) W.c[i] = (float)((X[i] - mean) / denom);

    // separable gaussian 1D weights, sigma = k/2; horizontal prescaled by k^2
    for (int k = 1; k <= 6; ++k) {
        double sigma = k / 2.0;
        double g[6], s = 0.0;
        for (int i = 0; i < k; ++i) {
            double a = i - (k - 1) / 2.0;
            g[i] = exp(-(a * a) / (2.0 * sigma * sigma));
            s += g[i];
        }
        for (int i = 0; i < 6; ++i) {
            if (i < k) {
                double gn = g[i] / s;
                W.wv[k - 1][i] = (float)gn;
                W.wh[k - 1][i] = (float)(gn * (double)(k * k));
            } else {
                W.wv[k - 1][i] = 0.0f;
                W.wh[k - 1][i] = 0.0f;
            }
        }
    }

    dim3 grid(512 / TILE, 512 / TILE, 64);
    dim3 block(32, 8, 1);
    hipLaunchKernelGGL(ldeb_kernel, grid, block, 0, stream, x, out, W);
}

// Round 2
// 57.866 us; speedup vs baseline: 1.2182x; 1.2182x over previous
//
#include <hip/hip_runtime.h>
#include <math.h>

// densemap = sum_k c_k * log2(relu(k^2 * conv_k(x)) + 1)
// conv_k = separable Gaussian (sigma = k/2), TF-SAME padding: pad_lo = (k-1)/2.
// Column/row window offsets union: -2..+3 (6 wide). k=1 kernel == identity (weight 1.0).

struct Weights {
    float wh[6][6]; // horizontal 1D gaussian weights, prescaled by k^2
    float wv[6][6]; // vertical 1D gaussian weights
    float c[6];     // regression slope coefficients
};

#define TX 64
#define TY 64
#define RPT 16        // rows per thread (block 64x4)
#define LDSW 69       // TX + 5 halo
#define LDSN (69*69)  // 4761

__global__ __launch_bounds__(256) void ldeb_kernel(const float* __restrict__ x,
                                                   float* __restrict__ out,
                                                   Weights W) {
    __shared__ float xs[LDSN];
    const int img = blockIdx.z;
    const int bx = blockIdx.x, by = blockIdx.y;
    const int x0 = bx * TX - 2, y0 = by * TY - 2;
    const float* __restrict__ xb = x + (size_t)img * 262144;
    const int tid = threadIdx.y * 64 + threadIdx.x;

    // stage 69x69 halo tile; interior blocks skip bounds clamps (uniform branch)
    if (bx >= 1 && bx <= 6 && by >= 1 && by <= 6) {
#pragma unroll
        for (int it = 0; it < 19; ++it) {
            int i = tid + it * 256;
            if (i < LDSN) {
                int r = i / LDSW, c = i - r * LDSW;
                xs[i] = xb[(y0 + r) * 512 + (x0 + c)];
            }
        }
    } else {
#pragma unroll
        for (int it = 0; it < 19; ++it) {
            int i = tid + it * 256;
            if (i < LDSN) {
                int r = i / LDSW, c = i - r * LDSW;
                int gy = y0 + r, gx = x0 + c;
                float v = 0.0f;
                if ((unsigned)gy < 512u && (unsigned)gx < 512u)
                    v = xb[gy * 512 + gx];
                xs[i] = v;
            }
        }
    }
    __syncthreads();

    const int lc = threadIdx.x;          // local col 0..63
    const int Lr0 = threadIdx.y * RPT;   // this thread's staged-row base
    const float* __restrict__ base = &xs[Lr0 * LDSW + lc];

    // 6-deep ring of horizontal-pass results; all indices compile-time after
    // full unroll -> stays in VGPRs (no scratch).
    float Hr[6][6];

#define HROW(i) { \
        const float* row = base + (i) * LDSW; \
        float v0 = row[0], v1 = row[1], v2 = row[2], \
              v3 = row[3], v4 = row[4], v5 = row[5]; \
        Hr[(i) % 6][0] = v2; /* k=1: identity */ \
        Hr[(i) % 6][1] = v2 * W.wh[1][0] + v3 * W.wh[1][1]; \
        Hr[(i) % 6][2] = v1 * W.wh[2][0] + v2 * W.wh[2][1] + v3 * W.wh[2][2]; \
        Hr[(i) % 6][3] = v1 * W.wh[3][0] + v2 * W.wh[3][1] + v3 * W.wh[3][2] \
                       + v4 * W.wh[3][3]; \
        Hr[(i) % 6][4] = v0 * W.wh[4][0] + v1 * W.wh[4][1] + v2 * W.wh[4][2] \
                       + v3 * W.wh[4][3] + v4 * W.wh[4][4]; \
        Hr[(i) % 6][5] = v0 * W.wh[5][0] + v1 * W.wh[5][1] + v2 * W.wh[5][2] \
                       + v3 * W.wh[5][3] + v4 * W.wh[5][4] + v5 * W.wh[5][5]; \
    }
#define SLOT(n) Hr[(n) % 6]

    // prologue: staged rows 0..4 of this thread's window
    HROW(0) HROW(1) HROW(2) HROW(3) HROW(4)

    float* __restrict__ ob = out + (size_t)img * 262144
                           + (size_t)(by * TY + Lr0) * 512 + bx * TX + lc;

#pragma unroll
    for (int r = 0; r < RPT; ++r) {
        HROW(r + 5)

        // vertical passes (pad_lo per k: 0,0,1,1,2,2); wv[0][0] == 1
        float s1 = SLOT(r + 2)[0];
        float s2 = SLOT(r + 2)[1] * W.wv[1][0] + SLOT(r + 3)[1] * W.wv[1][1];
        float s3 = SLOT(r + 1)[2] * W.wv[2][0] + SLOT(r + 2)[2] * W.wv[2][1]
                 + SLOT(r + 3)[2] * W.wv[2][2];
        float s4 = SLOT(r + 1)[3] * W.wv[3][0] + SLOT(r + 2)[3] * W.wv[3][1]
                 + SLOT(r + 3)[3] * W.wv[3][2] + SLOT(r + 4)[3] * W.wv[3][3];
        float s5 = SLOT(r + 0)[4] * W.wv[4][0] + SLOT(r + 1)[4] * W.wv[4][1]
                 + SLOT(r + 2)[4] * W.wv[4][2] + SLOT(r + 3)[4] * W.wv[4][3]
                 + SLOT(r + 4)[4] * W.wv[4][4];
        float s6 = SLOT(r + 0)[5] * W.wv[5][0] + SLOT(r + 1)[5] * W.wv[5][1]
                 + SLOT(r + 2)[5] * W.wv[5][2] + SLOT(r + 3)[5] * W.wv[5][3]
                 + SLOT(r + 4)[5] * W.wv[5][4] + SLOT(r + 5)[5] * W.wv[5][5];

        // native v_log_f32 (computes log2); input >= 1 so no edge cases
        float y1 = __builtin_amdgcn_logf(fmaxf(s1, 0.0f) + 1.0f);
        float y2 = __builtin_amdgcn_logf(fmaxf(s2, 0.0f) + 1.0f);
        float y3 = __builtin_amdgcn_logf(fmaxf(s3, 0.0f) + 1.0f);
        float y4 = __builtin_amdgcn_logf(fmaxf(s4, 0.0f) + 1.0f);
        float y5 = __builtin_amdgcn_logf(fmaxf(s5, 0.0f) + 1.0f);
        float y6 = __builtin_amdgcn_logf(fmaxf(s6, 0.0f) + 1.0f);

        float acc = W.c[0] * y1 + W.c[1] * y2 + W.c[2] * y3
                  + W.c[3] * y4 + W.c[4] * y5 + W.c[5] * y6;

        ob[r * 512] = acc;
    }
#undef HROW
#undef SLOT
}

extern "C" void kernel_launch(void* const* d_in, const int* in_sizes, int n_in,
                              void* d_out, int out_size, void* d_ws, size_t ws_size,
                              hipStream_t stream) {
    const float* x = (const float*)d_in[0];
    float* out = (float*)d_out;

    Weights W;
    // regression coefficients: c_k = (X_k - mean(X)) / sum((X - mean)^2), X_k = log2(k)
    double X[6], mean = 0.0;
    for (int k = 1; k <= 6; ++k) { X[k - 1] = log2((double)k); mean += X[k - 1]; }
    mean /= 6.0;
    double denom = 0.0;
    for (int i = 0; i < 6; ++i) { double xc = X[i] - mean; denom += xc * xc; }
    for (int i = 0; i < 6; ++i) W.c[i] = (float)((X[i] - mean) / denom);

    // separable gaussian 1D weights, sigma = k/2; horizontal prescaled by k^2
    for (int k = 1; k <= 6; ++k) {
        double sigma = k / 2.0;
        double g[6], s = 0.0;
        for (int i = 0; i < k; ++i) {
            double a = i - (k - 1) / 2.0;
            g[i] = exp(-(a * a) / (2.0 * sigma * sigma));
            s += g[i];
        }
        for (int i = 0; i < 6; ++i) {
            if (i < k) {
                double gn = g[i] / s;
                W.wv[k - 1][i] = (float)gn;
                W.wh[k - 1][i] = (float)(gn * (double)(k * k));
            } else {
                W.wv[k - 1][i] = 0.0f;
                W.wh[k - 1][i] = 0.0f;
            }
        }
    }

    dim3 grid(512 / TX, 512 / TY, 64);
    dim3 block(64, 4, 1);
    hipLaunchKernelGGL(ldeb_kernel, grid, block, 0, stream, x, out, W);
}

// Round 3
// 50.231 us; speedup vs baseline: 1.4034x; 1.1520x over previous
//
#include <hip/hip_runtime.h>
#include <math.h>

// densemap = sum_k c_k * log2(relu(k^2 * conv_k(x)) + 1)
// conv_k = separable Gaussian (sigma = k/2), TF-SAME padding: pad_lo = (k-1)/2.
// Column/row window offsets union: -2..+3 (6 wide). k=1 kernel == identity.
//
// Tile: 64x64 outputs per block. Staged region: 69 rows x 72 cols, with
// x0a = bx*64 - 4 so every row segment is 16B-aligned and every float4 is
// fully in-range or fully out-of-range (512 % 4 == 0).

struct Weights {
    float wh[6][6]; // horizontal 1D gaussian weights, prescaled by k^2
    float wv[6][6]; // vertical 1D gaussian weights
    float c[6];     // regression slope coefficients
};

#define TXO 64
#define TYO 64
#define RPT 16          // rows per thread (block 64x4)
#define LDSW 72         // floats per staged row (16B-aligned stride)
#define SROWS 69        // staged rows: outputs -2..+66 relative to row base
#define NF4 (SROWS * 18)  // 1242 float4s per tile

#define GLOAD_LDS16(gp, lp) __builtin_amdgcn_global_load_lds( \
    (const __attribute__((address_space(1))) unsigned int*)(gp), \
    (__attribute__((address_space(3))) unsigned int*)(lp), 16, 0, 0)

__global__ __launch_bounds__(256) void ldeb_kernel(const float* __restrict__ x,
                                                   float* __restrict__ out,
                                                   Weights W) {
    __shared__ float xs[SROWS * LDSW];
    const int img = blockIdx.z;
    const int bx = blockIdx.x, by = blockIdx.y;
    const int x0a = bx * TXO - 4;      // aligned staged-col base
    const int y0 = by * TYO - 2;       // staged-row base
    const float* __restrict__ xb = x + (size_t)img * 262144;
    const int tid = threadIdx.y * 64 + threadIdx.x;

    if (bx >= 1 && bx <= 6 && by >= 1 && by <= 6) {
        // interior: direct global->LDS, 16B per lane, LDS dest linear in tid
#pragma unroll
        for (int it = 0; it < 5; ++it) {
            int i = tid + it * 256;
            if (i < NF4) {
                int row = i / 18;
                int c4 = i - row * 18;
                const float* gp = xb + (size_t)(y0 + row) * 512 + x0a + 4 * c4;
                GLOAD_LDS16(gp, &xs[i * 4]);
            }
        }
    } else {
        // border: reg-staged float4 with whole-float4 zero-fill
#pragma unroll
        for (int it = 0; it < 5; ++it) {
            int i = tid + it * 256;
            if (i < NF4) {
                int row = i / 18;
                int c4 = i - row * 18;
                int gy = y0 + row;
                int gc = x0a + 4 * c4;
                float4 v = make_float4(0.f, 0.f, 0.f, 0.f);
                if ((unsigned)gy < 512u && (unsigned)gc < 512u)
                    v = *(const float4*)(xb + (size_t)gy * 512 + gc);
                *(float4*)&xs[i * 4] = v;
            }
        }
    }
    __syncthreads();

    const int lc = threadIdx.x;          // local col 0..63
    const int Lr0 = threadIdx.y * RPT;   // this thread's staged-row base
    // output col = bx*64 + lc; staged col index = (out_col - 2) - x0a = lc + 2
    const float* __restrict__ base = &xs[Lr0 * LDSW + lc + 2];

    // 6-deep ring of horizontal-pass results; all indices compile-time after
    // full unroll -> stays in VGPRs (no scratch).
    float Hr[6][6];

#define HROW(i) { \
        const float* row = base + (i) * LDSW; \
        float v0 = row[0], v1 = row[1], v2 = row[2], \
              v3 = row[3], v4 = row[4], v5 = row[5]; \
        Hr[(i) % 6][0] = v2; /* k=1: identity */ \
        Hr[(i) % 6][1] = v2 * W.wh[1][0] + v3 * W.wh[1][1]; \
        Hr[(i) % 6][2] = v1 * W.wh[2][0] + v2 * W.wh[2][1] + v3 * W.wh[2][2]; \
        Hr[(i) % 6][3] = v1 * W.wh[3][0] + v2 * W.wh[3][1] + v3 * W.wh[3][2] \
                       + v4 * W.wh[3][3]; \
        Hr[(i) % 6][4] = v0 * W.wh[4][0] + v1 * W.wh[4][1] + v2 * W.wh[4][2] \
                       + v3 * W.wh[4][3] + v4 * W.wh[4][4]; \
        Hr[(i) % 6][5] = v0 * W.wh[5][0] + v1 * W.wh[5][1] + v2 * W.wh[5][2] \
                       + v3 * W.wh[5][3] + v4 * W.wh[5][4] + v5 * W.wh[5][5]; \
    }
#define SLOT(n) Hr[(n) % 6]

    // prologue: staged rows 0..4 of this thread's window
    HROW(0) HROW(1) HROW(2) HROW(3) HROW(4)

    float* __restrict__ ob = out + (size_t)img * 262144
                           + (size_t)(by * TYO + Lr0) * 512 + bx * TXO + lc;

#pragma unroll
    for (int r = 0; r < RPT; ++r) {
        HROW(r + 5)

        // vertical passes (pad_lo per k: 0,0,1,1,2,2); wv[0][0] == 1
        float s1 = SLOT(r + 2)[0];
        float s2 = SLOT(r + 2)[1] * W.wv[1][0] + SLOT(r + 3)[1] * W.wv[1][1];
        float s3 = SLOT(r + 1)[2] * W.wv[2][0] + SLOT(r + 2)[2] * W.wv[2][1]
                 + SLOT(r + 3)[2] * W.wv[2][2];
        float s4 = SLOT(r + 1)[3] * W.wv[3][0] + SLOT(r + 2)[3] * W.wv[3][1]
                 + SLOT(r + 3)[3] * W.wv[3][2] + SLOT(r + 4)[3] * W.wv[3][3];
        float s5 = SLOT(r + 0)[4] * W.wv[4][0] + SLOT(r + 1)[4] * W.wv[4][1]
                 + SLOT(r + 2)[4] * W.wv[4][2] + SLOT(r + 3)[4] * W.wv[4][3]
                 + SLOT(r + 4)[4] * W.wv[4][4];
        float s6 = SLOT(r + 0)[5] * W.wv[5][0] + SLOT(r + 1)[5] * W.wv[5][1]
                 + SLOT(r + 2)[5] * W.wv[5][2] + SLOT(r + 3)[5] * W.wv[5][3]
                 + SLOT(r + 4)[5] * W.wv[5][4] + SLOT(r + 5)[5] * W.wv[5][5];

        // native v_log_f32 (computes log2); input >= 1 so no edge cases
        float y1 = __builtin_amdgcn_logf(fmaxf(s1, 0.0f) + 1.0f);
        float y2 = __builtin_amdgcn_logf(fmaxf(s2, 0.0f) + 1.0f);
        float y3 = __builtin_amdgcn_logf(fmaxf(s3, 0.0f) + 1.0f);
        float y4 = __builtin_amdgcn_logf(fmaxf(s4, 0.0f) + 1.0f);
        float y5 = __builtin_amdgcn_logf(fmaxf(s5, 0.0f) + 1.0f);
        float y6 = __builtin_amdgcn_logf(fmaxf(s6, 0.0f) + 1.0f);

        float acc = W.c[0] * y1 + W.c[1] * y2 + W.c[2] * y3
                  + W.c[3] * y4 + W.c[4] * y5 + W.c[5] * y6;

        ob[r * 512] = acc;
    }
#undef HROW
#undef SLOT
}

extern "C" void kernel_launch(void* const* d_in, const int* in_sizes, int n_in,
                              void* d_out, int out_size, void* d_ws, size_t ws_size,
                              hipStream_t stream) {
    const float* x = (const float*)d_in[0];
    float* out = (float*)d_out;

    Weights W;
    // regression coefficients: c_k = (X_k - mean(X)) / sum((X - mean)^2), X_k = log2(k)
    double X[6], mean = 0.0;
    for (int k = 1; k <= 6; ++k) { X[k - 1] = log2((double)k); mean += X[k - 1]; }
    mean /= 6.0;
    double denom = 0.0;
    for (int i = 0; i < 6; ++i) { double xc = X[i] - mean; denom += xc * xc; }
    for (int i = 0; i < 6; ++i) W.c[i] = (float)((X[i] - mean) / denom);

    // separable gaussian 1D weights, sigma = k/2; horizontal prescaled by k^2
    for (int k = 1; k <= 6; ++k) {
        double sigma = k / 2.0;
        double g[6], s = 0.0;
        for (int i = 0; i < k; ++i) {
            double a = i - (k - 1) / 2.0;
            g[i] = exp(-(a * a) / (2.0 * sigma * sigma));
            s += g[i];
        }
        for (int i = 0; i < 6; ++i) {
            if (i < k) {
                double gn = g[i] / s;
                W.wv[k - 1][i] = (float)gn;
                W.wh[k - 1][i] = (float)(gn * (double)(k * k));
            } else {
                W.wv[k - 1][i] = 0.0f;
                W.wh[k - 1][i] = 0.0f;
            }
        }
    }

    dim3 grid(512 / TXO, 512 / TYO, 64);
    dim3 block(64, 4, 1);
    hipLaunchKernelGGL(ldeb_kernel, grid, block, 0, stream, x, out, W);
}

// Round 4
// 49.544 us; speedup vs baseline: 1.4228x; 1.0139x over previous
//
#include <hip/hip_runtime.h>
#include <math.h>

// densemap = sum_k c_k * log2(relu(k^2 * conv_k(x)) + 1)
// conv_k = separable Gaussian (sigma = k/2), TF-SAME padding: pad_lo = (k-1)/2.
// Column/row window offsets union: -2..+3 (6 wide). k=1 kernel == identity.
//
// Tile: 64x64 outputs per block, 16 rows per thread (block 64x4).
// Staged region: 69 rows x 72 cols, x0a = bx*64 - 4 so all row segments are
// 16B-aligned and float4s are fully in- or out-of-range (512 % 4 == 0).
// Compute phase is fully straight-line (macro-expanded, literal indices) so
// the 6-deep H ring is guaranteed to live in VGPRs, never scratch.

struct Weights {
    // symmetric-pair horizontal coefficients (prescaled by k^2)
    float h2, h3a, h3b, h4a, h4b, h5a, h5b, h5c, h6a, h6b, h6c;
    float wv[6][6]; // vertical 1D gaussian weights
    float c[6];     // regression slope coefficients
};

#define TXO 64
#define TYO 64
#define RPT 16          // rows per thread (block 64x4)
#define LDSW 72         // floats per staged row (16B-aligned stride)
#define SROWS 69        // staged rows: outputs -2..+66 relative to row base
#define NF4 (SROWS * 18)  // 1242 float4s per tile

#define GLOAD_LDS16(gp, lp) __builtin_amdgcn_global_load_lds( \
    (const __attribute__((address_space(1))) unsigned int*)(gp), \
    (__attribute__((address_space(3))) unsigned int*)(lp), 16, 0, 0)

__global__ __launch_bounds__(256) void ldeb_kernel(const float* __restrict__ x,
                                                   float* __restrict__ out,
                                                   Weights W) {
    __shared__ float xs[SROWS * LDSW];
    const int img = blockIdx.z;
    const int bx = blockIdx.x, by = blockIdx.y;
    const int x0a = bx * TXO - 4;      // aligned staged-col base
    const int y0 = by * TYO - 2;       // staged-row base
    const float* __restrict__ xb = x + (size_t)img * 262144;
    const int tid = threadIdx.y * 64 + threadIdx.x;

    if (bx >= 1 && bx <= 6 && by >= 1 && by <= 6) {
        // interior: direct global->LDS, 16B/lane, LDS dest linear in tid
#pragma unroll
        for (int it = 0; it < 5; ++it) {
            int i = tid + it * 256;
            if (i < NF4) {
                int row = i / 18;
                int c4 = i - row * 18;
                const float* gp = xb + (size_t)(y0 + row) * 512 + x0a + 4 * c4;
                GLOAD_LDS16(gp, &xs[i * 4]);
            }
        }
    } else {
        // border: reg-staged float4 with whole-float4 zero-fill
#pragma unroll
        for (int it = 0; it < 5; ++it) {
            int i = tid + it * 256;
            if (i < NF4) {
                int row = i / 18;
                int c4 = i - row * 18;
                int gy = y0 + row;
                int gc = x0a + 4 * c4;
                float4 v = make_float4(0.f, 0.f, 0.f, 0.f);
                if ((unsigned)gy < 512u && (unsigned)gc < 512u)
                    v = *(const float4*)(xb + (size_t)gy * 512 + gc);
                *(float4*)&xs[i * 4] = v;
            }
        }
    }
    __syncthreads();

    const int lc = threadIdx.x;          // local col 0..63
    const int Lr0 = threadIdx.y * RPT;   // this thread's staged-row base
    // output col = bx*64 + lc; staged col index = (out_col - 2) - x0a = lc + 2
    const float* __restrict__ base = &xs[Lr0 * LDSW + lc + 2];

    float Hr[6][6];  // 6-deep ring; all indices are ICEs -> VGPRs

// horizontal pass, symmetric-pair form: 5 adds + 11 mul/fma
#define HROW(i) { \
        const float* row = base + (i) * LDSW; \
        float v0 = row[0], v1 = row[1], v2 = row[2], \
              v3 = row[3], v4 = row[4], v5 = row[5]; \
        float s23 = v2 + v3, s14 = v1 + v4, s05 = v0 + v5; \
        float s13 = v1 + v3, s04 = v0 + v4; \
        Hr[(i) % 6][0] = v2; /* k=1: identity */ \
        Hr[(i) % 6][1] = W.h2  * s23; \
        Hr[(i) % 6][2] = W.h3a * s13 + W.h3b * v2; \
        Hr[(i) % 6][3] = W.h4a * s14 + W.h4b * s23; \
        Hr[(i) % 6][4] = W.h5a * s04 + W.h5b * s13 + W.h5c * v2; \
        Hr[(i) % 6][5] = W.h6a * s05 + W.h6b * s14 + W.h6c * s23; \
    }
#define SLOT(n) Hr[(n) % 6]

// vertical pass + log + slope for output row r (pad_lo per k: 0,0,1,1,2,2)
#define VPASS(r) { \
        float s1 = SLOT((r) + 2)[0]; \
        float s2 = SLOT((r) + 2)[1] * W.wv[1][0] + SLOT((r) + 3)[1] * W.wv[1][1]; \
        float s3 = SLOT((r) + 1)[2] * W.wv[2][0] + SLOT((r) + 2)[2] * W.wv[2][1] \
                 + SLOT((r) + 3)[2] * W.wv[2][2]; \
        float s4 = SLOT((r) + 1)[3] * W.wv[3][0] + SLOT((r) + 2)[3] * W.wv[3][1] \
                 + SLOT((r) + 3)[3] * W.wv[3][2] + SLOT((r) + 4)[3] * W.wv[3][3]; \
        float s5 = SLOT((r) + 0)[4] * W.wv[4][0] + SLOT((r) + 1)[4] * W.wv[4][1] \
                 + SLOT((r) + 2)[4] * W.wv[4][2] + SLOT((r) + 3)[4] * W.wv[4][3] \
                 + SLOT((r) + 4)[4] * W.wv[4][4]; \
        float s6 = SLOT((r) + 0)[5] * W.wv[5][0] + SLOT((r) + 1)[5] * W.wv[5][1] \
                 + SLOT((r) + 2)[5] * W.wv[5][2] + SLOT((r) + 3)[5] * W.wv[5][3] \
                 + SLOT((r) + 4)[5] * W.wv[5][4] + SLOT((r) + 5)[5] * W.wv[5][5]; \
        float y1 = __builtin_amdgcn_logf(fmaxf(s1, 0.0f) + 1.0f); \
        float y2 = __builtin_amdgcn_logf(fmaxf(s2, 0.0f) + 1.0f); \
        float y3 = __builtin_amdgcn_logf(fmaxf(s3, 0.0f) + 1.0f); \
        float y4 = __builtin_amdgcn_logf(fmaxf(s4, 0.0f) + 1.0f); \
        float y5 = __builtin_amdgcn_logf(fmaxf(s5, 0.0f) + 1.0f); \
        float y6 = __builtin_amdgcn_logf(fmaxf(s6, 0.0f) + 1.0f); \
        ob[(r) * 512] = W.c[0] * y1 + W.c[1] * y2 + W.c[2] * y3 \
                      + W.c[3] * y4 + W.c[4] * y5 + W.c[5] * y6; \
    }

#define ITER(r) HROW((r) + 5) VPASS(r)

    float* __restrict__ ob = out + (size_t)img * 262144
                           + (size_t)(by * TYO + Lr0) * 512 + bx * TXO + lc;

    // prologue: staged rows 0..4 of this thread's window
    HROW(0) HROW(1) HROW(2) HROW(3) HROW(4)
    // straight-line body: every index an integer constant expression
    ITER(0)  ITER(1)  ITER(2)  ITER(3)
    ITER(4)  ITER(5)  ITER(6)  ITER(7)
    ITER(8)  ITER(9)  ITER(10) ITER(11)
    ITER(12) ITER(13) ITER(14) ITER(15)

#undef ITER
#undef VPASS
#undef HROW
#undef SLOT
}

extern "C" void kernel_launch(void* const* d_in, const int* in_sizes, int n_in,
                              void* d_out, int out_size, void* d_ws, size_t ws_size,
                              hipStream_t stream) {
    const float* x = (const float*)d_in[0];
    float* out = (float*)d_out;

    Weights W;
    // regression coefficients: c_k = (X_k - mean(X)) / sum((X - mean)^2), X_k = log2(k)
    double X[6], mean = 0.0;
    for (int k = 1; k <= 6; ++k) { X[k - 1] = log2((double)k); mean += X[k - 1]; }
    mean /= 6.0;
    double denom = 0.0;
    for (int i = 0; i < 6; ++i) { double xc = X[i] - mean; denom += xc * xc; }
    for (int i = 0; i < 6; ++i) W.c[i] = (float)((X[i] - mean) / denom);

    // separable gaussian 1D weights, sigma = k/2
    float wh[6][6];
    for (int k = 1; k <= 6; ++k) {
        double sigma = k / 2.0;
        double g[6], s = 0.0;
        for (int i = 0; i < k; ++i) {
            double a = i - (k - 1) / 2.0;
            g[i] = exp(-(a * a) / (2.0 * sigma * sigma));
            s += g[i];
        }
        for (int i = 0; i < 6; ++i) {
            if (i < k) {
                double gn = g[i] / s;
                W.wv[k - 1][i] = (float)gn;
                wh[k - 1][i] = (float)(gn * (double)(k * k)); // horizontal prescaled by k^2
            } else {
                W.wv[k - 1][i] = 0.0f;
                wh[k - 1][i] = 0.0f;
            }
        }
    }
    // symmetric-pair horizontal coefficients
    W.h2  = wh[1][0];
    W.h3a = wh[2][0]; W.h3b = wh[2][1];
    W.h4a = wh[3][0]; W.h4b = wh[3][1];
    W.h5a = wh[4][0]; W.h5b = wh[4][1]; W.h5c = wh[4][2];
    W.h6a = wh[5][0]; W.h6b = wh[5][1]; W.h6c = wh[5][2];

    dim3 grid(512 / TXO, 512 / TYO, 64);
    dim3 block(64, 4, 1);
    hipLaunchKernelGGL(ldeb_kernel, grid, block, 0, stream, x, out, W);
}

// Round 5
// 49.423 us; speedup vs baseline: 1.4263x; 1.0025x over previous
//
#include <hip/hip_runtime.h>
#include <math.h>

// densemap = sum_k c_k * log2(relu(k^2 * conv_k(x)) + 1)
// conv_k = separable Gaussian (sigma = k/2), TF-SAME padding: pad_lo = (k-1)/2.
// Column/row window offsets union: -2..+3 (6 wide). k=1 kernel == identity.
//
// Tile: 64x64 outputs per block, 16 rows per thread (block 64x4).
// Staged region: 69 rows x 72 cols, x0a = bx*64 - 4 so all row segments are
// 16B-aligned and float4s are fully in- or out-of-range (512 % 4 == 0).
// Compute phase is fully straight-line (macro-expanded, literal indices).
//
// __launch_bounds__(256, 4): min 4 waves/EU -> 128-reg budget per wave.
// Without this, LDS (19.5KB -> 8 blocks/CU) makes the backend target 8
// waves/SIMD = 64 total regs/wave, and the allocator shuttles the 6x6 H-ring
// through AGPRs (v_accvgpr_write/read = VALU) -- the measured ~2x VALU bloat
// at a constant VGPR_Count=28.

struct Weights {
    // symmetric-pair horizontal coefficients (prescaled by k^2)
    float h2, h3a, h3b, h4a, h4b, h5a, h5b, h5c, h6a, h6b, h6c;
    float wv[6][6]; // vertical 1D gaussian weights
    float c[6];     // regression slope coefficients
};

#define TXO 64
#define TYO 64
#define RPT 16          // rows per thread (block 64x4)
#define LDSW 72         // floats per staged row (16B-aligned stride)
#define SROWS 69        // staged rows: outputs -2..+66 relative to row base
#define NF4 (SROWS * 18)  // 1242 float4s per tile

#define GLOAD_LDS16(gp, lp) __builtin_amdgcn_global_load_lds( \
    (const __attribute__((address_space(1))) unsigned int*)(gp), \
    (__attribute__((address_space(3))) unsigned int*)(lp), 16, 0, 0)

__global__ __launch_bounds__(256, 4) void ldeb_kernel(const float* __restrict__ x,
                                                      float* __restrict__ out,
                                                      Weights W) {
    __shared__ float xs[SROWS * LDSW];
    const int img = blockIdx.z;
    const int bx = blockIdx.x, by = blockIdx.y;
    const int x0a = bx * TXO - 4;      // aligned staged-col base
    const int y0 = by * TYO - 2;       // staged-row base
    const float* __restrict__ xb = x + (size_t)img * 262144;
    const int tid = threadIdx.y * 64 + threadIdx.x;

    if (bx >= 1 && bx <= 6 && by >= 1 && by <= 6) {
        // interior: direct global->LDS, 16B/lane, LDS dest linear in tid
#pragma unroll
        for (int it = 0; it < 5; ++it) {
            int i = tid + it * 256;
            if (i < NF4) {
                int row = i / 18;
                int c4 = i - row * 18;
                const float* gp = xb + (size_t)(y0 + row) * 512 + x0a + 4 * c4;
                GLOAD_LDS16(gp, &xs[i * 4]);
            }
        }
    } else {
        // border: reg-staged float4 with whole-float4 zero-fill
#pragma unroll
        for (int it = 0; it < 5; ++it) {
            int i = tid + it * 256;
            if (i < NF4) {
                int row = i / 18;
                int c4 = i - row * 18;
                int gy = y0 + row;
                int gc = x0a + 4 * c4;
                float4 v = make_float4(0.f, 0.f, 0.f, 0.f);
                if ((unsigned)gy < 512u && (unsigned)gc < 512u)
                    v = *(const float4*)(xb + (size_t)gy * 512 + gc);
                *(float4*)&xs[i * 4] = v;
            }
        }
    }
    __syncthreads();

    const int lc = threadIdx.x;          // local col 0..63
    const int Lr0 = threadIdx.y * RPT;   // this thread's staged-row base
    // output col = bx*64 + lc; staged col index = (out_col - 2) - x0a = lc + 2
    const float* __restrict__ base = &xs[Lr0 * LDSW + lc + 2];

    float Hr[6][6];  // 6-deep ring; all indices are ICEs -> VGPRs

// horizontal pass, symmetric-pair form: 5 adds + 11 mul/fma
#define HROW(i) { \
        const float* row = base + (i) * LDSW; \
        float v0 = row[0], v1 = row[1], v2 = row[2], \
              v3 = row[3], v4 = row[4], v5 = row[5]; \
        float s23 = v2 + v3, s14 = v1 + v4, s05 = v0 + v5; \
        float s13 = v1 + v3, s04 = v0 + v4; \
        Hr[(i) % 6][0] = v2; /* k=1: identity */ \
        Hr[(i) % 6][1] = W.h2  * s23; \
        Hr[(i) % 6][2] = W.h3a * s13 + W.h3b * v2; \
        Hr[(i) % 6][3] = W.h4a * s14 + W.h4b * s23; \
        Hr[(i) % 6][4] = W.h5a * s04 + W.h5b * s13 + W.h5c * v2; \
        Hr[(i) % 6][5] = W.h6a * s05 + W.h6b * s14 + W.h6c * s23; \
    }
#define SLOT(n) Hr[(n) % 6]

// vertical pass + log + slope for output row r (pad_lo per k: 0,0,1,1,2,2)
#define VPASS(r) { \
        float s1 = SLOT((r) + 2)[0]; \
        float s2 = SLOT((r) + 2)[1] * W.wv[1][0] + SLOT((r) + 3)[1] * W.wv[1][1]; \
        float s3 = SLOT((r) + 1)[2] * W.wv[2][0] + SLOT((r) + 2)[2] * W.wv[2][1] \
                 + SLOT((r) + 3)[2] * W.wv[2][2]; \
        float s4 = SLOT((r) + 1)[3] * W.wv[3][0] + SLOT((r) + 2)[3] * W.wv[3][1] \
                 + SLOT((r) + 3)[3] * W.wv[3][2] + SLOT((r) + 4)[3] * W.wv[3][3]; \
        float s5 = SLOT((r) + 0)[4] * W.wv[4][0] + SLOT((r) + 1)[4] * W.wv[4][1] \
                 + SLOT((r) + 2)[4] * W.wv[4][2] + SLOT((r) + 3)[4] * W.wv[4][3] \
                 + SLOT((r) + 4)[4] * W.wv[4][4]; \
        float s6 = SLOT((r) + 0)[5] * W.wv[5][0] + SLOT((r) + 1)[5] * W.wv[5][1] \
                 + SLOT((r) + 2)[5] * W.wv[5][2] + SLOT((r) + 3)[5] * W.wv[5][3] \
                 + SLOT((r) + 4)[5] * W.wv[5][4] + SLOT((r) + 5)[5] * W.wv[5][5]; \
        float y1 = __builtin_amdgcn_logf(fmaxf(s1, 0.0f) + 1.0f); \
        float y2 = __builtin_amdgcn_logf(fmaxf(s2, 0.0f) + 1.0f); \
        float y3 = __builtin_amdgcn_logf(fmaxf(s3, 0.0f) + 1.0f); \
        float y4 = __builtin_amdgcn_logf(fmaxf(s4, 0.0f) + 1.0f); \
        float y5 = __builtin_amdgcn_logf(fmaxf(s5, 0.0f) + 1.0f); \
        float y6 = __builtin_amdgcn_logf(fmaxf(s6, 0.0f) + 1.0f); \
        ob[(r) * 512] = W.c[0] * y1 + W.c[1] * y2 + W.c[2] * y3 \
                      + W.c[3] * y4 + W.c[4] * y5 + W.c[5] * y6; \
    }

#define ITER(r) HROW((r) + 5) VPASS(r)

    float* __restrict__ ob = out + (size_t)img * 262144
                           + (size_t)(by * TYO + Lr0) * 512 + bx * TXO + lc;

    // prologue: staged rows 0..4 of this thread's window
    HROW(0) HROW(1) HROW(2) HROW(3) HROW(4)
    // straight-line body: every index an integer constant expression
    ITER(0)  ITER(1)  ITER(2)  ITER(3)
    ITER(4)  ITER(5)  ITER(6)  ITER(7)
    ITER(8)  ITER(9)  ITER(10) ITER(11)
    ITER(12) ITER(13) ITER(14) ITER(15)

#undef ITER
#undef VPASS
#undef HROW
#undef SLOT
}

extern "C" void kernel_launch(void* const* d_in, const int* in_sizes, int n_in,
                              void* d_out, int out_size, void* d_ws, size_t ws_size,
                              hipStream_t stream) {
    const float* x = (const float*)d_in[0];
    float* out = (float*)d_out;

    Weights W;
    // regression coefficients: c_k = (X_k - mean(X)) / sum((X - mean)^2), X_k = log2(k)
    double X[6], mean = 0.0;
    for (int k = 1; k <= 6; ++k) { X[k - 1] = log2((double)k); mean += X[k - 1]; }
    mean /= 6.0;
    double denom = 0.0;
    for (int i = 0; i < 6; ++i) { double xc = X[i] - mean; denom += xc * xc; }
    for (int i = 0; i < 6; ++i) W.c[i] = (float)((X[i] - mean) / denom);

    // separable gaussian 1D weights, sigma = k/2
    float wh[6][6];
    for (int k = 1; k <= 6; ++k) {
        double sigma = k / 2.0;
        double g[6], s = 0.0;
        for (int i = 0; i < k; ++i) {
            double a = i - (k - 1) / 2.0;
            g[i] = exp(-(a * a) / (2.0 * sigma * sigma));
            s += g[i];
        }
        for (int i = 0; i < 6; ++i) {
            if (i < k) {
                double gn = g[i] / s;
                W.wv[k - 1][i] = (float)gn;
                wh[k - 1][i] = (float)(gn * (double)(k * k)); // horizontal prescaled by k^2
            } else {
                W.wv[k - 1][i] = 0.0f;
                wh[k - 1][i] = 0.0f;
            }
        }
    }
    // symmetric-pair horizontal coefficients
    W.h2  = wh[1][0];
    W.h3a = wh[2][0]; W.h3b = wh[2][1];
    W.h4a = wh[3][0]; W.h4b = wh[3][1];
    W.h5a = wh[4][0]; W.h5b = wh[4][1]; W.h5c = wh[4][2];
    W.h6a = wh[5][0]; W.h6b = wh[5][1]; W.h6c = wh[5][2];

    dim3 grid(512 / TXO, 512 / TYO, 64);
    dim3 block(64, 4, 1);
    hipLaunchKernelGGL(ldeb_kernel, grid, block, 0, stream, x, out, W);
}

// Round 6
// 44.173 us; speedup vs baseline: 1.5959x; 1.1188x over previous
//
#include <hip/hip_runtime.h>
#include <math.h>

// densemap = sum_k c_k * log2(relu(k^2 * conv_k(x)) + 1)
// conv_k = separable Gaussian (sigma = k/2), TF-SAME padding: pad_lo = (k-1)/2.
// Column/row window offsets union: -2..+3 (6 wide). k=1 kernel == identity.
//
// Tile: 64x32 outputs per block, 8 rows per thread (block 64x4).
// Staged region: 37 rows x 72 cols (10.7 KB LDS), x0a = bx*64 - 4 so all row
// segments are 16B-aligned and float4s are fully in- or out-of-range.
// Small LDS -> 8 resident blocks/CU (thread-cap) -> stage-drain of one block
// hides under compute of others (latency-bound fix; VALU ~16us, HBM ~21us).

struct Weights {
    // symmetric-pair horizontal coefficients (prescaled by k^2)
    float h2, h3a, h3b, h4a, h4b, h5a, h5b, h5c, h6a, h6b, h6c;
    float wv[6][6]; // vertical 1D gaussian weights
    float c[6];     // regression slope coefficients
};

#define TXO 64
#define TYO 32
#define RPT 8           // rows per thread (block 64x4)
#define LDSW 72         // floats per staged row (16B-aligned stride)
#define SROWS 37        // staged rows: outputs -2..+34 relative to row base
#define NF4 (SROWS * 18)  // 666 float4s per tile

#define GLOAD_LDS16(gp, lp) __builtin_amdgcn_global_load_lds( \
    (const __attribute__((address_space(1))) unsigned int*)(gp), \
    (__attribute__((address_space(3))) unsigned int*)(lp), 16, 0, 0)

__global__ __launch_bounds__(256, 4) void ldeb_kernel(const float* __restrict__ x,
                                                      float* __restrict__ out,
                                                      Weights W) {
    __shared__ float xs[SROWS * LDSW];
    const int img = blockIdx.z;
    const int bx = blockIdx.x, by = blockIdx.y;
    const int x0a = bx * TXO - 4;      // aligned staged-col base
    const int y0 = by * TYO - 2;       // staged-row base
    const float* __restrict__ xb = x + (size_t)img * 262144;
    const int tid = threadIdx.y * 64 + threadIdx.x;

    if (bx >= 1 && bx <= 6 && by >= 1 && by <= 14) {
        // interior: direct global->LDS, 16B/lane, LDS dest linear in tid
#pragma unroll
        for (int it = 0; it < 3; ++it) {
            int i = tid + it * 256;
            if (i < NF4) {
                int row = i / 18;
                int c4 = i - row * 18;
                const float* gp = xb + (size_t)(y0 + row) * 512 + x0a + 4 * c4;
                GLOAD_LDS16(gp, &xs[i * 4]);
            }
        }
    } else {
        // border: reg-staged float4 with whole-float4 zero-fill
#pragma unroll
        for (int it = 0; it < 3; ++it) {
            int i = tid + it * 256;
            if (i < NF4) {
                int row = i / 18;
                int c4 = i - row * 18;
                int gy = y0 + row;
                int gc = x0a + 4 * c4;
                float4 v = make_float4(0.f, 0.f, 0.f, 0.f);
                if ((unsigned)gy < 512u && (unsigned)gc < 512u)
                    v = *(const float4*)(xb + (size_t)gy * 512 + gc);
                *(float4*)&xs[i * 4] = v;
            }
        }
    }
    __syncthreads();

    const int lc = threadIdx.x;          // local col 0..63
    const int Lr0 = threadIdx.y * RPT;   // this thread's staged-row base
    // output col = bx*64 + lc; staged col index = (out_col - 2) - x0a = lc + 2
    const float* __restrict__ base = &xs[Lr0 * LDSW + lc + 2];

    float Hr[6][6];  // 6-deep ring; all indices are ICEs -> VGPRs

// horizontal pass, symmetric-pair form: 5 adds + 11 mul/fma
#define HROW(i) { \
        const float* row = base + (i) * LDSW; \
        float v0 = row[0], v1 = row[1], v2 = row[2], \
              v3 = row[3], v4 = row[4], v5 = row[5]; \
        float s23 = v2 + v3, s14 = v1 + v4, s05 = v0 + v5; \
        float s13 = v1 + v3, s04 = v0 + v4; \
        Hr[(i) % 6][0] = v2; /* k=1: identity */ \
        Hr[(i) % 6][1] = W.h2  * s23; \
        Hr[(i) % 6][2] = W.h3a * s13 + W.h3b * v2; \
        Hr[(i) % 6][3] = W.h4a * s14 + W.h4b * s23; \
        Hr[(i) % 6][4] = W.h5a * s04 + W.h5b * s13 + W.h5c * v2; \
        Hr[(i) % 6][5] = W.h6a * s05 + W.h6b * s14 + W.h6c * s23; \
    }
#define SLOT(n) Hr[(n) % 6]

// vertical pass + log + slope for output row r (pad_lo per k: 0,0,1,1,2,2)
#define VPASS(r) { \
        float s1 = SLOT((r) + 2)[0]; \
        float s2 = SLOT((r) + 2)[1] * W.wv[1][0] + SLOT((r) + 3)[1] * W.wv[1][1]; \
        float s3 = SLOT((r) + 1)[2] * W.wv[2][0] + SLOT((r) + 2)[2] * W.wv[2][1] \
                 + SLOT((r) + 3)[2] * W.wv[2][2]; \
        float s4 = SLOT((r) + 1)[3] * W.wv[3][0] + SLOT((r) + 2)[3] * W.wv[3][1] \
                 + SLOT((r) + 3)[3] * W.wv[3][2] + SLOT((r) + 4)[3] * W.wv[3][3]; \
        float s5 = SLOT((r) + 0)[4] * W.wv[4][0] + SLOT((r) + 1)[4] * W.wv[4][1] \
                 + SLOT((r) + 2)[4] * W.wv[4][2] + SLOT((r) + 3)[4] * W.wv[4][3] \
                 + SLOT((r) + 4)[4] * W.wv[4][4]; \
        float s6 = SLOT((r) + 0)[5] * W.wv[5][0] + SLOT((r) + 1)[5] * W.wv[5][1] \
                 + SLOT((r) + 2)[5] * W.wv[5][2] + SLOT((r) + 3)[5] * W.wv[5][3] \
                 + SLOT((r) + 4)[5] * W.wv[5][4] + SLOT((r) + 5)[5] * W.wv[5][5]; \
        float y1 = __builtin_amdgcn_logf(fmaxf(s1, 0.0f) + 1.0f); \
        float y2 = __builtin_amdgcn_logf(fmaxf(s2, 0.0f) + 1.0f); \
        float y3 = __builtin_amdgcn_logf(fmaxf(s3, 0.0f) + 1.0f); \
        float y4 = __builtin_amdgcn_logf(fmaxf(s4, 0.0f) + 1.0f); \
        float y5 = __builtin_amdgcn_logf(fmaxf(s5, 0.0f) + 1.0f); \
        float y6 = __builtin_amdgcn_logf(fmaxf(s6, 0.0f) + 1.0f); \
        ob[(r) * 512] = W.c[0] * y1 + W.c[1] * y2 + W.c[2] * y3 \
                      + W.c[3] * y4 + W.c[4] * y5 + W.c[5] * y6; \
    }

#define ITER(r) HROW((r) + 5) VPASS(r)

    float* __restrict__ ob = out + (size_t)img * 262144
                           + (size_t)(by * TYO + Lr0) * 512 + bx * TXO + lc;

    // prologue: staged rows 0..4 of this thread's window
    HROW(0) HROW(1) HROW(2) HROW(3) HROW(4)
    // straight-line body: every index an integer constant expression
    ITER(0) ITER(1) ITER(2) ITER(3)
    ITER(4) ITER(5) ITER(6) ITER(7)

#undef ITER
#undef VPASS
#undef HROW
#undef SLOT
}

extern "C" void kernel_launch(void* const* d_in, const int* in_sizes, int n_in,
                              void* d_out, int out_size, void* d_ws, size_t ws_size,
                              hipStream_t stream) {
    const float* x = (const float*)d_in[0];
    float* out = (float*)d_out;

    Weights W;
    // regression coefficients: c_k = (X_k - mean(X)) / sum((X - mean)^2), X_k = log2(k)
    double X[6], mean = 0.0;
    for (int k = 1; k <= 6; ++k) { X[k - 1] = log2((double)k); mean += X[k - 1]; }
    mean /= 6.0;
    double denom = 0.0;
    for (int i = 0; i < 6; ++i) { double xc = X[i] - mean; denom += xc * xc; }
    for (int i = 0; i < 6; ++i) W.c[i] = (float)((X[i] - mean) / denom);

    // separable gaussian 1D weights, sigma = k/2
    float wh[6][6];
    for (int k = 1; k <= 6; ++k) {
        double sigma = k / 2.0;
        double g[6], s = 0.0;
        for (int i = 0; i < k; ++i) {
            double a = i - (k - 1) / 2.0;
            g[i] = exp(-(a * a) / (2.0 * sigma * sigma));
            s += g[i];
        }
        for (int i = 0; i < 6; ++i) {
            if (i < k) {
                double gn = g[i] / s;
                W.wv[k - 1][i] = (float)gn;
                wh[k - 1][i] = (float)(gn * (double)(k * k)); // horizontal prescaled by k^2
            } else {
                W.wv[k - 1][i] = 0.0f;
                wh[k - 1][i] = 0.0f;
            }
        }
    }
    // symmetric-pair horizontal coefficients
    W.h2  = wh[1][0];
    W.h3a = wh[2][0]; W.h3b = wh[2][1];
    W.h4a = wh[3][0]; W.h4b = wh[3][1];
    W.h5a = wh[4][0]; W.h5b = wh[4][1]; W.h5c = wh[4][2];
    W.h6a = wh[5][0]; W.h6b = wh[5][1]; W.h6c = wh[5][2];

    dim3 grid(512 / TXO, 512 / TYO, 64);
    dim3 block(64, 4, 1);
    hipLaunchKernelGGL(ldeb_kernel, grid, block, 0, stream, x, out, W);
}